// Round 3
// baseline (150.479 us; speedup 1.0000x reference)
//
#include <hip/hip_runtime.h>
#include <stdint.h>

#define UNITS 4096
#define NB0   2048   // 11-bit digit bins
#define RPB   8      // rows per block; grid = 16384/8 = 2048 = 8 blocks/CU resident

// LDS-only barrier: drain this wave's LDS ops (atomics/writes) then s_barrier,
// WITHOUT draining vmcnt — keeps the next-row global prefetch in flight
// across the whole selection phase (unlike __syncthreads, which the compiler
// precedes with s_waitcnt vmcnt(0)).
__device__ __forceinline__ void lds_barrier() {
    asm volatile("s_waitcnt lgkmcnt(0)" ::: "memory");
    __builtin_amdgcn_s_barrier();
}

// order-preserving float->uint map (ascending): neg -> ~b, pos -> b | msb
__device__ __forceinline__ uint32_t flipu(uint32_t b) {
    return b ^ (uint32_t)(((int32_t)b >> 31) | (int32_t)0x80000000);
}

__global__ __launch_bounds__(256, 8) void ksparse_select_kernel(
        const float* __restrict__ X, float* __restrict__ out, int kidx, int nrows) {
    __shared__ uint32_t hist[NB0];   // 8 KiB block-shared histogram
    __shared__ uint32_t wsum[4];
    __shared__ uint32_t sel[2];      // {selected bin, rank within bin}

    const int t    = threadIdx.x;
    const int w    = t >> 6;
    const int lane = t & 63;

    uint4* h4 = reinterpret_cast<uint4*>(hist);
    const uint4 z4 = make_uint4(0u, 0u, 0u, 0u);
    h4[2 * t]     = z4;   // thread t owns bins [8t, 8t+8)
    h4[2 * t + 1] = z4;

    const int row0 = (int)blockIdx.x * RPB;
    if (row0 >= nrows) return;                       // block-uniform
    const int rcnt = min(RPB, nrows - row0);

    // initial load (row0)
    float4 v[4];
    {
        const float4* Xv = reinterpret_cast<const float4*>(X + (size_t)row0 * UNITS);
#pragma unroll
        for (int j = 0; j < 4; ++j) v[j] = Xv[j * 256 + t];
    }

    lds_barrier();  // hist zeroed everywhere

#pragma unroll 1
    for (int r = 0; r < rcnt; ++r) {
        const int row = row0 + r;

        // convert current row to ordered uints (consumes prefetched v)
        uint32_t uu[16];
#pragma unroll
        for (int j = 0; j < 4; ++j) {
            uu[4 * j + 0] = flipu(__float_as_uint(v[j].x));
            uu[4 * j + 1] = flipu(__float_as_uint(v[j].y));
            uu[4 * j + 2] = flipu(__float_as_uint(v[j].z));
            uu[4 * j + 3] = flipu(__float_as_uint(v[j].w));
        }

        // prefetch next row NOW — stays in flight across the whole selection
        if (r + 1 < rcnt) {
            const float4* Xn = reinterpret_cast<const float4*>(X + (size_t)(row + 1) * UNITS);
#pragma unroll
            for (int j = 0; j < 4; ++j) v[j] = Xn[j * 256 + t];
        }

        // pass-0 histogram: top 11 bits
#pragma unroll
        for (int e = 0; e < 16; ++e) atomicAdd(&hist[uu[e] >> 21], 1u);

        uint32_t kk   = (uint32_t)kidx;
        uint32_t pref = 0;

#pragma unroll
        for (int pass = 0; pass < 3; ++pass) {
            lds_barrier();  // histogram atomics drained + visible

            // read my 8 bins, immediately re-zero them (only owner touches)
            uint4 a = h4[2 * t];
            uint4 b = h4[2 * t + 1];
            h4[2 * t]     = z4;
            h4[2 * t + 1] = z4;
            uint32_t h[8] = {a.x, a.y, a.z, a.w, b.x, b.y, b.z, b.w};
            uint32_t s = 0;
#pragma unroll
            for (int i = 0; i < 8; ++i) s += h[i];

            // wave inclusive scan of per-thread sums
            uint32_t incl = s;
#pragma unroll
            for (int d = 1; d < 64; d <<= 1) {
                uint32_t x = __shfl_up(incl, d);
                if (lane >= d) incl += x;
            }
            if (lane == 63) wsum[w] = incl;
            lds_barrier();  // wsum ready; bin-zeroing also drained here

            uint32_t off = 0;
#pragma unroll
            for (int ww = 0; ww < 4; ++ww) off += (ww < w) ? wsum[ww] : 0u;
            incl += off;
            const uint32_t excl = incl - s;

            if (kk >= excl && kk < excl + s) {   // exactly one thread
                uint32_t c = excl, bin = 0, rem = 0;
#pragma unroll
                for (int i = 0; i < 8; ++i) {
                    if (kk < c + h[i]) { bin = 8u * t + i; rem = kk - c; break; }
                    c += h[i];
                }
                sel[0] = bin;
                sel[1] = rem;
            }
            lds_barrier();  // sel ready

            const uint32_t bin = sel[0];
            kk = sel[1];

            if (pass == 0) {
                pref = bin;  // bits [31:21]
#pragma unroll
                for (int e = 0; e < 16; ++e)
                    if ((uu[e] >> 21) == pref) atomicAdd(&hist[(uu[e] >> 10) & 2047u], 1u);
            } else if (pass == 1) {
                pref = (pref << 11) | bin;  // bits [31:10]
#pragma unroll
                for (int e = 0; e < 16; ++e)
                    if ((uu[e] >> 10) == pref) atomicAdd(&hist[uu[e] & 1023u], 1u);
            } else {
                pref = (pref << 10) | bin;  // full 32-bit pattern of theta
            }
        }

        const uint32_t tu = pref;

        // masked write-back; unflip + threshold compare in uint domain
        float4* Ov = reinterpret_cast<float4*>(out + (size_t)row * UNITS);
#pragma unroll
        for (int j = 0; j < 4; ++j) {
            float4 o;
            {
                uint32_t u = uu[4 * j + 0];
                uint32_t m = ~(uint32_t)((int32_t)u >> 31) | 0x80000000u;
                o.x = (u >= tu) ? __uint_as_float(u ^ m) : 0.0f;
            }
            {
                uint32_t u = uu[4 * j + 1];
                uint32_t m = ~(uint32_t)((int32_t)u >> 31) | 0x80000000u;
                o.y = (u >= tu) ? __uint_as_float(u ^ m) : 0.0f;
            }
            {
                uint32_t u = uu[4 * j + 2];
                uint32_t m = ~(uint32_t)((int32_t)u >> 31) | 0x80000000u;
                o.z = (u >= tu) ? __uint_as_float(u ^ m) : 0.0f;
            }
            {
                uint32_t u = uu[4 * j + 3];
                uint32_t m = ~(uint32_t)((int32_t)u >> 31) | 0x80000000u;
                o.w = (u >= tu) ? __uint_as_float(u ^ m) : 0.0f;
            }
            Ov[j * 256 + t] = o;
        }
    }
}

extern "C" void kernel_launch(void* const* d_in, const int* in_sizes, int n_in,
                              void* d_out, int out_size, void* d_ws, size_t ws_size,
                              hipStream_t stream) {
    const float* X = (const float*)d_in[0];
    float* out = (float*)d_out;
    const int rows = in_sizes[0] / UNITS;
    const int kidx = (int)(0.7 * UNITS);  // 2867
    const int grid = (rows + RPB - 1) / RPB;
    ksparse_select_kernel<<<grid, 256, 0, stream>>>(X, out, kidx, rows);
}